// Round 13
// baseline (302.285 us; speedup 1.0000x reference)
//
#include <hip/hip_runtime.h>

#define DIM 512
#define NTOK 2304
#define HEADS 8
#define HD 64
#define LN_EPS 1e-5f
#define BNC 2359296   // B*N*C = 2*2304*512
#define QSC 0.18033688011112042f   // 0.125 * log2(e): softmax in exp2 domain

typedef __attribute__((ext_vector_type(8))) short short8;
typedef __attribute__((ext_vector_type(4))) short sh4;
typedef __attribute__((ext_vector_type(4))) float f32x4;

__device__ __forceinline__ short f2bf(float f) {
    union { float f; unsigned u; } x; x.f = f;
    unsigned r = (x.u + 0x7fffu + ((x.u >> 16) & 1u)) >> 16;
    return (short)(r & 0xffffu);
}
__device__ __forceinline__ unsigned fbits(float f) {
    union { float f; unsigned u; } x; x.f = f; return x.u;
}
// async global->LDS DMA, 16B/lane; lds dest = wave-uniform base + lane*16
__device__ __forceinline__ void gl2lds(const short* g, short* l) {
    __builtin_amdgcn_global_load_lds(
        (const __attribute__((address_space(1))) unsigned int*)g,
        (__attribute__((address_space(3))) unsigned int*)l, 16, 0, 0);
}

// -------- LN stats, computed ONCE per token --------
__global__ void __launch_bounds__(256)
k_stats(const float* __restrict__ x, const float* __restrict__ y,
        float* __restrict__ mu, float* __restrict__ rs) {
    __shared__ float pS[4][64], pQ[4][64];
    int bid = blockIdx.x, tid = threadIdx.x;   // 144 blocks: sb*36 + nt
    int nt = bid % 36, sb = bid / 36;
    int s = sb >> 1, b = sb & 1;
    int n0 = nt * 64;
    const float* src = (s ? y : x) + (size_t)b * DIM * NTOK;
    int nl = tid & 63, part = tid >> 6;
    const float* p = src + n0 + nl;
    float sum = 0.f, sq = 0.f;
    for (int c = part * 128; c < part * 128 + 128; c++) {
        float v = p[(size_t)c * NTOK];
        sum += v; sq += v * v;
    }
    pS[part][nl] = sum; pQ[part][nl] = sq;
    __syncthreads();
    if (tid < 64) {
        float ts = pS[0][tid] + pS[1][tid] + pS[2][tid] + pS[3][tid];
        float tq = pQ[0][tid] + pQ[1][tid] + pQ[2][tid] + pQ[3][tid];
        float m = ts * (1.0f / DIM);
        float var = tq * (1.0f / DIM) - m * m;
        mu[sb * NTOK + n0 + tid] = m;
        rs[sb * NTOK + n0 + tid] = rsqrtf(var + LN_EPS);
    }
}

// -------- fused pre: normalize+transpose (blocks 0..1151) + weight transpose (1152..1343) --------
__global__ void k_pre(const float* __restrict__ x, const float* __restrict__ y,
                      const float* __restrict__ qv_w, const float* __restrict__ k_w,
                      const float* __restrict__ qv_b, const float* __restrict__ k_b,
                      const float* __restrict__ gx, const float* __restrict__ bx,
                      const float* __restrict__ gy, const float* __restrict__ by,
                      const float* __restrict__ mu, const float* __restrict__ rs,
                      short* __restrict__ T, short* __restrict__ Wt,
                      float* __restrict__ bias) {
    __shared__ __align__(16) float tile[64][65];
    int bkid = blockIdx.x, tid = threadIdx.x;
    if (bkid < 1152) {
        int nt = bkid % 36, ct = (bkid / 36) % 8, sb = bkid / 288;
        int s = sb >> 1, b = sb & 1;
        int n0 = nt * 64, c0 = ct * 64;
        const float* src = (s ? y : x) + (size_t)b * DIM * NTOK;
        for (int slot = tid; slot < 1024; slot += 256) {
            int r = slot >> 4, q = slot & 15;
            const float* p = src + (size_t)(c0 + r) * NTOK + n0 + q * 4;
            float4 v = *(const float4*)p;
            tile[r][q*4+0] = v.x; tile[r][q*4+1] = v.y;
            tile[r][q*4+2] = v.z; tile[r][q*4+3] = v.w;
        }
        __syncthreads();
        const float* g  = s ? gy : gx;
        const float* be = s ? by : bx;
        int nr = tid >> 2, cg = tid & 3;
        float m  = mu[sb * NTOK + n0 + nr];
        float r_ = rs[sb * NTOK + n0 + nr];
        short8 o0, o1;
        for (int i = 0; i < 8; i++) {
            int c = c0 + cg * 16 + i;
            o0[i] = f2bf((tile[cg*16+i][nr] - m) * r_ * g[c] + be[c]);
        }
        for (int i = 0; i < 8; i++) {
            int c = c0 + cg * 16 + 8 + i;
            o1[i] = f2bf((tile[cg*16+8+i][nr] - m) * r_ * g[c] + be[c]);
        }
        short* dst = T + ((size_t)sb * NTOK + n0 + nr) * DIM + c0 + cg * 16;
        *(short8*)dst = o0;
        *(short8*)(dst + 8) = o1;
        return;
    }
    // ---- weight transpose blocks ----
    int idx = bkid - 1152;
    int jt = idx % 24, ct = idx / 24;
    int j0 = jt * 64, c0 = ct * 64;
    if (ct == 0 && tid < 64) {
        int j = j0 + tid;
        bias[j] = (j < 1024) ? qv_b[j] : k_b[j - 1024];
    }
    for (int slot = tid; slot < 1024; slot += 256) {
        int r = slot >> 4, q = slot & 15;
        int c = c0 + r;
        float4 v;
        if (j0 < 1024) v = *(const float4*)(qv_w + (size_t)c * 1024 + j0 + q * 4);
        else           v = *(const float4*)(k_w  + (size_t)c * 512  + (j0 - 1024) + q * 4);
        tile[r][q*4+0] = v.x; tile[r][q*4+1] = v.y;
        tile[r][q*4+2] = v.z; tile[r][q*4+3] = v.w;
    }
    __syncthreads();
    int jr = tid >> 2, cg = tid & 3;
    short8 o0, o1;
    for (int i = 0; i < 8; i++) o0[i] = f2bf(tile[cg*16+i][jr]);
    for (int i = 0; i < 8; i++) o1[i] = f2bf(tile[cg*16+8+i][jr]);
    short* dst = Wt + (size_t)(j0 + jr) * DIM + c0 + cg * 16;
    *(short8*)dst = o0;
    *(short8*)(dst + 8) = o1;
}

// -------- GEMM: 128x128 tile, double-buffered DMA staging (1 barrier/kk), swapped-operand epilogue --------
__global__ void __launch_bounds__(256)
k_gemm(const short* __restrict__ T, const short* __restrict__ Wt,
       const float* __restrict__ bias, short* __restrict__ QVK,
       short* __restrict__ VT) {
    __shared__ __align__(16) short Abuf[2][128 * 64];
    __shared__ __align__(16) short Bbuf[2][128 * 64];
    int n0 = blockIdx.x * 128, j0 = blockIdx.y * 128, sb = blockIdx.z;
    int tid = threadIdx.x;
    int w = tid >> 6, l = tid & 63;
    int wr = w >> 1, wc = w & 1;
    int lrow = l & 15, quad = l >> 4;
    int r_in = (l >> 3) & 7, cc = l & 7;
    int ch = cc ^ r_in;                       // swizzled source chunk
    int sw0 = (quad ^ (lrow & 7)) * 8;        // frag-read chunk offset (shorts)
    const short* Ab = T + (size_t)sb * NTOK * DIM;
    f32x4 acc[4][4] = {};

    #pragma unroll
    for (int inst = 0; inst < 4; inst++) {
        int R = w * 32 + inst * 8 + r_in;
        gl2lds(Ab + (size_t)(n0 + R) * 512 + 0 * 64 + ch * 8, &Abuf[0][(w * 32 + inst * 8) * 64]);
        gl2lds(Wt + (size_t)(j0 + R) * 512 + 0 * 64 + ch * 8, &Bbuf[0][(w * 32 + inst * 8) * 64]);
    }
    int cur = 0;
    for (int kk = 0; kk < 8; kk++) {
        __syncthreads();                      // buf[cur] DMA drained; buf[cur^1] readers done
        if (kk + 1 < 8) {
            #pragma unroll
            for (int inst = 0; inst < 4; inst++) {
                int R = w * 32 + inst * 8 + r_in;
                gl2lds(Ab + (size_t)(n0 + R) * 512 + (kk + 1) * 64 + ch * 8,
                       &Abuf[cur ^ 1][(w * 32 + inst * 8) * 64]);
                gl2lds(Wt + (size_t)(j0 + R) * 512 + (kk + 1) * 64 + ch * 8,
                       &Bbuf[cur ^ 1][(w * 32 + inst * 8) * 64]);
            }
        }
        #pragma unroll
        for (int c2 = 0; c2 < 2; c2++) {
            int off = c2 ? (sw0 ^ 32) : sw0;
            short8 af[4], bf[4];
            #pragma unroll
            for (int i = 0; i < 4; i++)
                af[i] = *(const short8*)&Abuf[cur][(wr*64 + i*16 + lrow) * 64 + off];
            #pragma unroll
            for (int j = 0; j < 4; j++)
                bf[j] = *(const short8*)&Bbuf[cur][(wc*64 + j*16 + lrow) * 64 + off];
            #pragma unroll
            for (int i = 0; i < 4; i++)
                #pragma unroll
                for (int j = 0; j < 4; j++)   // SWAPPED: C rows = jj (bf), cols = n (af)
                    acc[i][j] = __builtin_amdgcn_mfma_f32_16x16x32_bf16(bf[j], af[i], acc[i][j], 0, 0, 0);
        }
        cur ^= 1;
    }
    // swapped C layout: element(i,j,reg): n = n0+wr*64+i*16+lrow, jj = j0+wc*64+j*16+quad*4+reg
    if (j0 >= 512 && j0 < 1024) {
        __syncthreads();               // main-loop LDS readers done
        short* sm = &Abuf[0][0];
        #pragma unroll
        for (int i = 0; i < 4; i++)
            #pragma unroll
            for (int j = 0; j < 4; j++) {
                int jb = wc * 64 + j * 16 + quad * 4;       // local jj base (mult of 4)
                int nloc = wr * 64 + i * 16 + lrow;
                float4 bv4 = *(const float4*)&bias[j0 + jb];
                float bvs[4] = {bv4.x, bv4.y, bv4.z, bv4.w};
                #pragma unroll
                for (int reg = 0; reg < 4; reg++) {
                    int jloc = jb + reg;
                    sm[jloc * 128 + (((nloc >> 3) ^ (jloc & 15)) * 8) + (nloc & 7)]
                        = f2bf(acc[i][j][reg] + bvs[reg]);
                }
            }
        __syncthreads();
        for (int slot = tid; slot < 2048; slot += 256) {
            int row = slot >> 4, seg = slot & 15;
            short8 v = *(const short8*)&sm[row * 128 + ((seg ^ (row & 15)) * 8)];
            *(short8*)(VT + ((size_t)sb * 512 + (j0 - 512) + row) * NTOK + n0 + seg * 8) = v;
        }
    } else {
        #pragma unroll
        for (int i = 0; i < 4; i++) {
            int n = n0 + wr * 64 + i * 16 + lrow;
            #pragma unroll
            for (int j = 0; j < 4; j++) {
                int jjb = j0 + wc * 64 + j * 16 + quad * 4;
                float4 bv4 = *(const float4*)&bias[jjb];
                float bvs[4] = {bv4.x, bv4.y, bv4.z, bv4.w};
                float sc = (jjb < 512) ? QSC : 1.0f;   // Q pre-scaled into exp2 domain
                sh4 pk;
                #pragma unroll
                for (int reg = 0; reg < 4; reg++)
                    pk[reg] = f2bf((acc[i][j][reg] + bvs[reg]) * sc);
                *(sh4*)&QVK[((size_t)sb * NTOK + n) * 1536 + jjb] = pk;   // 8B store
            }
        }
    }
}

// ---------------- flash attention: barrier-free, K/V/Q fragments direct from L2 ----------------
// R25: R12's threshold-lowering showed the harness's 256MiB workspace fill
// (~42us) was the hidden fixed cost, and that all non-attn kernels are <42us.
// K/V per (yb) is 590KB = L2-resident (XCD-pinned by the id%8 swizzle), so LDS
// staging was Common-mistake #7: paying LDS-pipe cycles + 2 barriers/tile for
// cached data. The swizzled-LDS fragment algebra inverts: logical chunk 'quad'
// of row r = global base + r*stride + quad*8 (+32 for chunk quad^4); per row
// the 4 quads cover one contiguous 64B segment. So: load K/V/Q MFMA fragments
// DIRECTLY from L2, delete all staging + dbuf + every __syncthreads. LDS keeps
// only the wave-private P round-trip (16KB/block -> high occupancy).
__global__ void __launch_bounds__(256)
k_attn(const short* __restrict__ QVK, const short* __restrict__ VT,
       float* __restrict__ out, float* __restrict__ Opart,
       float* __restrict__ lbuf, int ntiles) {
    __shared__ __align__(16) short Ps[4][32 * 64];   // wave-private P (32 rows each)
    int id = blockIdx.x;
    int half = id / 576;              // KV slice index (0..ns-1)
    int rid = id % 576;
    int xcd = rid & 7, rem = rid >> 3;   // rem 0..71
    int qt = rem % 18, yhi = rem / 18;   // 18 q-tiles of 128 rows; yhi 0..3
    int yb = yhi * 8 + xcd;           // 0..31
    int br = yb >> 4;
    int b  = (yb >> 3) & 1;
    int h  = yb & 7;
    int tid = threadIdx.x;
    int w = tid >> 6, l = tid & 63;
    int lrow = l & 15, quad = l >> 4;
    int sw0 = (quad ^ (lrow & 7)) * 8;   // P swizzle only (LDS)
    int n0 = qt * 128;
    int m_base = half * ntiles * 64;
    const short* Qg = QVK + ((size_t)(br * 2 + b) * NTOK) * 1536 + h * 64;           // exp2-scaled Q
    const short* Kg = QVK + ((size_t)((1 - br) * 2 + b) * NTOK) * 1536 + 1024 + h * 64;
    const short* Vg = VT + ((size_t)(br * 2 + b) * 512 + h * 64) * NTOK;

    // Q fragments direct from L2: row n0+w*32+qb*16+lrow, chunks quad / quad^4
    short8 bq[2][2];
    #pragma unroll
    for (int qb = 0; qb < 2; qb++) {
        const short* qrow = Qg + (size_t)(n0 + w * 32 + qb * 16 + lrow) * 1536 + quad * 8;
        bq[qb][0] = *(const short8*)(qrow);
        bq[qb][1] = *(const short8*)(qrow + 32);
    }
    short* Pw = Ps[w];

    // per-lane K/V fragment bases (advance per tile)
    const short* Kp = Kg + (size_t)(m_base + lrow) * 1536 + quad * 8;   // +sub*16*1536 per sub
    const short* Vp = Vg + (size_t)lrow * NTOK + m_base + quad * 8;     // +ddt*16*NTOK per ddt

    short8 ones;
    #pragma unroll
    for (int i = 0; i < 8; i++) ones[i] = (short)0x3F80;   // bf16 1.0

    f32x4 Oacc[2][4] = {};
    f32x4 lacc[2] = {};

    for (int mt = 0; mt < ntiles; mt++) {
        // QK^T: K fragments direct from L2
        #pragma unroll
        for (int sub = 0; sub < 4; sub++) {
            const short* krow = Kp + (size_t)(sub * 16) * 1536;
            short8 ak0 = *(const short8*)(krow);
            short8 ak1 = *(const short8*)(krow + 32);
            #pragma unroll
            for (int qb = 0; qb < 2; qb++) {
                f32x4 a = {};
                a = __builtin_amdgcn_mfma_f32_16x16x32_bf16(ak0, bq[qb][0], a, 0, 0, 0);
                a = __builtin_amdgcn_mfma_f32_16x16x32_bf16(ak1, bq[qb][1], a, 0, 0, 0);
                float p0 = __builtin_amdgcn_exp2f(a[0]), p1 = __builtin_amdgcn_exp2f(a[1]);
                float p2 = __builtin_amdgcn_exp2f(a[2]), p3 = __builtin_amdgcn_exp2f(a[3]);
                uint2 pk;
                pk.x = __builtin_amdgcn_perm(fbits(p1), fbits(p0), 0x07060302u);
                pk.y = __builtin_amdgcn_perm(fbits(p3), fbits(p2), 0x07060302u);
                *(uint2*)&Pw[(qb * 16 + lrow) * 64 +
                             (((2 * sub + (quad >> 1)) ^ (lrow & 7)) * 8) + (quad & 1) * 4] = pk;
            }
        }

        // PV + l-sum: P from LDS (same-wave dep), V fragments direct from L2
        short8 ap[2][2];
        #pragma unroll
        for (int qb = 0; qb < 2; qb++) {
            ap[qb][0] = *(const short8*)&Pw[(qb * 16 + lrow) * 64 + sw0];
            ap[qb][1] = *(const short8*)&Pw[(qb * 16 + lrow) * 64 + (sw0 ^ 32)];
            lacc[qb] = __builtin_amdgcn_mfma_f32_16x16x32_bf16(ones, ap[qb][0], lacc[qb], 0, 0, 0);
            lacc[qb] = __builtin_amdgcn_mfma_f32_16x16x32_bf16(ones, ap[qb][1], lacc[qb], 0, 0, 0);
        }
        #pragma unroll
        for (int ddt = 0; ddt < 4; ddt++) {
            const short* vrow = Vp + (size_t)(ddt * 16) * NTOK;
            short8 av0 = *(const short8*)(vrow);
            short8 av1 = *(const short8*)(vrow + 32);
            #pragma unroll
            for (int qb = 0; qb < 2; qb++) {
                Oacc[qb][ddt] = __builtin_amdgcn_mfma_f32_16x16x32_bf16(av0, ap[qb][0], Oacc[qb][ddt], 0, 0, 0);
                Oacc[qb][ddt] = __builtin_amdgcn_mfma_f32_16x16x32_bf16(av1, ap[qb][1], Oacc[qb][ddt], 0, 0, 0);
            }
        }
        Kp += (size_t)64 * 1536;   // next 64 K rows
        Vp += 64;                  // next 64 V cols
    }

    // epilogue: unnormalized partial O + partial l (combined by k_norm)
    #pragma unroll
    for (int qb = 0; qb < 2; qb++) {
        int n = n0 + w * 32 + qb * 16 + lrow;
        if (quad == 0) lbuf[half * (32 * NTOK) + yb * NTOK + n] = lacc[qb][0];
        #pragma unroll
        for (int ddt = 0; ddt < 4; ddt++) {
            float4 o;
            o.x = Oacc[qb][ddt][0];
            o.y = Oacc[qb][ddt][1];
            o.z = Oacc[qb][ddt][2];
            o.w = Oacc[qb][ddt][3];
            if (half == 0) {
                if (br == 0)
                    *(float4*)&out[((size_t)b * NTOK + n) * 512 + h * 64 + ddt * 16 + quad * 4] = o;
                else
                    *(float4*)&out[(size_t)BNC + ((size_t)(h * 2 + b) * NTOK + n) * 64 + ddt * 16 + quad * 4] = o;
            } else {
                *(float4*)&Opart[(size_t)(half - 1) * 4718592 +
                                 ((size_t)yb * NTOK + n) * 64 + ddt * 16 + quad * 4] = o;
            }
        }
    }
}

// ---------------- combine + normalize: out = (out + sum Opart) / (sum l) ----------------
__global__ void __launch_bounds__(256)
k_norm(float* __restrict__ out, const float* __restrict__ Opart,
       const float* __restrict__ lbuf, int ns) {
    int i = blockIdx.x * 256 + threadIdx.x;   // float4 index, 1,179,648 total
    int o = i * 4;
    int yb, n, d;
    if (o < BNC) {
        int b = o / (NTOK * 512);
        int r = o % (NTOK * 512);
        n = r >> 9;
        int c = r & 511;
        d = c & 63;
        yb = b * 8 + (c >> 6);
    } else {
        int o2 = o - BNC;
        int hb = o2 / (NTOK * 64);
        n = (o2 >> 6) % NTOK;
        d = o2 & 63;
        yb = 16 + (hb & 1) * 8 + (hb >> 1);
    }
    int li = yb * NTOK + n;
    float lsum = 0.f;
    for (int k = 0; k < ns; k++) lsum += lbuf[k * (32 * NTOK) + li];
    float linv = 1.f / lsum;
    float4 a = *(const float4*)&out[o];
    for (int k = 1; k < ns; k++) {
        float4 q = *(const float4*)&Opart[(size_t)(k - 1) * 4718592 + (size_t)li * 64 + d];
        a.x += q.x; a.y += q.y; a.z += q.z; a.w += q.w;
    }
    a.x *= linv; a.y *= linv; a.z *= linv; a.w *= linv;
    *(float4*)&out[o] = a;
}

extern "C" void kernel_launch(void* const* d_in, const int* in_sizes, int n_in,
                              void* d_out, int out_size, void* d_ws, size_t ws_size,
                              hipStream_t stream) {
    const float* x     = (const float*)d_in[0];
    const float* y     = (const float*)d_in[1];
    const float* k_w   = (const float*)d_in[2];
    const float* k_b   = (const float*)d_in[3];
    const float* qv_w  = (const float*)d_in[4];
    const float* qv_b  = (const float*)d_in[5];
    const float* lnx_g = (const float*)d_in[6];
    const float* lnx_b = (const float*)d_in[7];
    const float* lny_g = (const float*)d_in[8];
    const float* lny_b = (const float*)d_in[9];
    float* out = (float*)d_out;

    char* ws = (char*)d_ws;
    float* bias = (float*)ws;                 // 6,144 B @ 0
    float* mu   = (float*)(ws + 6144);        // 36,864 B
    float* rs   = (float*)(ws + 43008);       // 36,864 B -> ends 79,872
    short* T    = (short*)(ws + 79872);       // 9,437,184 B -> ends 9,517,056
    short* Wt   = (short*)(ws + 9517056);     // 1,572,864 B -> ends 11,089,920
    short* QVK  = (short*)(ws + 11089920);    // 28,311,552 B -> ends 39,401,472
    short* VT   = (short*)(ws + 39401472);    // 9,437,184 B -> ends 48,838,656
    float* lbuf = (float*)(ws + 48838656);    // 1,179,648 B -> ends 50,018,304
    float* Opart= (float*)(ws + 50018304);    // up to 3 x 18,874,368 B -> ends 106,641,408

    // KV-split degree: 4 if the partial-O slabs fit in ws (R9/R10 proved they do), else 2.
    int ns = (ws_size >= 50018304ull + 3ull * 18874368ull) ? 4 : 2;
    int ntiles = 36 / ns;

    k_stats<<<144, 256, 0, stream>>>(x, y, mu, rs);
    k_pre  <<<1344, 256, 0, stream>>>(x, y, qv_w, k_w, qv_b, k_b,
                                      lnx_g, lnx_b, lny_g, lny_b, mu, rs, T, Wt, bias);
    k_gemm <<<dim3(18, 12, 4), 256, 0, stream>>>(T, Wt, bias, QVK, VT);
    k_attn <<<576 * ns, 256, 0, stream>>>(QVK, VT, out, Opart, lbuf, ntiles);
    k_norm <<<4608, 256, 0, stream>>>(out, Opart, lbuf, ns);
}

// Round 14
// 205.749 us; speedup vs baseline: 1.4692x; 1.4692x over previous
//
#include <hip/hip_runtime.h>

#define DIM 512
#define NTOK 2304
#define HEADS 8
#define HD 64
#define LN_EPS 1e-5f
#define BNC 2359296   // B*N*C = 2*2304*512
#define QSC 0.18033688011112042f   // 0.125 * log2(e): softmax in exp2 domain

typedef __attribute__((ext_vector_type(8))) short short8;
typedef __attribute__((ext_vector_type(4))) short sh4;
typedef __attribute__((ext_vector_type(4))) float f32x4;

__device__ __forceinline__ short f2bf(float f) {
    union { float f; unsigned u; } x; x.f = f;
    unsigned r = (x.u + 0x7fffu + ((x.u >> 16) & 1u)) >> 16;
    return (short)(r & 0xffffu);
}
__device__ __forceinline__ unsigned fbits(float f) {
    union { float f; unsigned u; } x; x.f = f; return x.u;
}
// async global->LDS DMA, 16B/lane; lds dest = wave-uniform base + lane*16
__device__ __forceinline__ void gl2lds(const short* g, short* l) {
    __builtin_amdgcn_global_load_lds(
        (const __attribute__((address_space(1))) unsigned int*)g,
        (__attribute__((address_space(3))) unsigned int*)l, 16, 0, 0);
}

// -------- LN stats, computed ONCE per token --------
__global__ void __launch_bounds__(256)
k_stats(const float* __restrict__ x, const float* __restrict__ y,
        float* __restrict__ mu, float* __restrict__ rs) {
    __shared__ float pS[4][64], pQ[4][64];
    int bid = blockIdx.x, tid = threadIdx.x;   // 144 blocks: sb*36 + nt
    int nt = bid % 36, sb = bid / 36;
    int s = sb >> 1, b = sb & 1;
    int n0 = nt * 64;
    const float* src = (s ? y : x) + (size_t)b * DIM * NTOK;
    int nl = tid & 63, part = tid >> 6;
    const float* p = src + n0 + nl;
    float sum = 0.f, sq = 0.f;
    for (int c = part * 128; c < part * 128 + 128; c++) {
        float v = p[(size_t)c * NTOK];
        sum += v; sq += v * v;
    }
    pS[part][nl] = sum; pQ[part][nl] = sq;
    __syncthreads();
    if (tid < 64) {
        float ts = pS[0][tid] + pS[1][tid] + pS[2][tid] + pS[3][tid];
        float tq = pQ[0][tid] + pQ[1][tid] + pQ[2][tid] + pQ[3][tid];
        float m = ts * (1.0f / DIM);
        float var = tq * (1.0f / DIM) - m * m;
        mu[sb * NTOK + n0 + tid] = m;
        rs[sb * NTOK + n0 + tid] = rsqrtf(var + LN_EPS);
    }
}

// -------- fused pre: normalize+transpose (blocks 0..1151) + weight transpose (1152..1343) --------
__global__ void k_pre(const float* __restrict__ x, const float* __restrict__ y,
                      const float* __restrict__ qv_w, const float* __restrict__ k_w,
                      const float* __restrict__ qv_b, const float* __restrict__ k_b,
                      const float* __restrict__ gx, const float* __restrict__ bx,
                      const float* __restrict__ gy, const float* __restrict__ by,
                      const float* __restrict__ mu, const float* __restrict__ rs,
                      short* __restrict__ T, short* __restrict__ Wt,
                      float* __restrict__ bias) {
    __shared__ __align__(16) float tile[64][65];
    int bkid = blockIdx.x, tid = threadIdx.x;
    if (bkid < 1152) {
        int nt = bkid % 36, ct = (bkid / 36) % 8, sb = bkid / 288;
        int s = sb >> 1, b = sb & 1;
        int n0 = nt * 64, c0 = ct * 64;
        const float* src = (s ? y : x) + (size_t)b * DIM * NTOK;
        for (int slot = tid; slot < 1024; slot += 256) {
            int r = slot >> 4, q = slot & 15;
            const float* p = src + (size_t)(c0 + r) * NTOK + n0 + q * 4;
            float4 v = *(const float4*)p;
            tile[r][q*4+0] = v.x; tile[r][q*4+1] = v.y;
            tile[r][q*4+2] = v.z; tile[r][q*4+3] = v.w;
        }
        __syncthreads();
        const float* g  = s ? gy : gx;
        const float* be = s ? by : bx;
        int nr = tid >> 2, cg = tid & 3;
        float m  = mu[sb * NTOK + n0 + nr];
        float r_ = rs[sb * NTOK + n0 + nr];
        short8 o0, o1;
        for (int i = 0; i < 8; i++) {
            int c = c0 + cg * 16 + i;
            o0[i] = f2bf((tile[cg*16+i][nr] - m) * r_ * g[c] + be[c]);
        }
        for (int i = 0; i < 8; i++) {
            int c = c0 + cg * 16 + 8 + i;
            o1[i] = f2bf((tile[cg*16+8+i][nr] - m) * r_ * g[c] + be[c]);
        }
        short* dst = T + ((size_t)sb * NTOK + n0 + nr) * DIM + c0 + cg * 16;
        *(short8*)dst = o0;
        *(short8*)(dst + 8) = o1;
        return;
    }
    // ---- weight transpose blocks ----
    int idx = bkid - 1152;
    int jt = idx % 24, ct = idx / 24;
    int j0 = jt * 64, c0 = ct * 64;
    if (ct == 0 && tid < 64) {
        int j = j0 + tid;
        bias[j] = (j < 1024) ? qv_b[j] : k_b[j - 1024];
    }
    for (int slot = tid; slot < 1024; slot += 256) {
        int r = slot >> 4, q = slot & 15;
        int c = c0 + r;
        float4 v;
        if (j0 < 1024) v = *(const float4*)(qv_w + (size_t)c * 1024 + j0 + q * 4);
        else           v = *(const float4*)(k_w  + (size_t)c * 512  + (j0 - 1024) + q * 4);
        tile[r][q*4+0] = v.x; tile[r][q*4+1] = v.y;
        tile[r][q*4+2] = v.z; tile[r][q*4+3] = v.w;
    }
    __syncthreads();
    int jr = tid >> 2, cg = tid & 3;
    short8 o0, o1;
    for (int i = 0; i < 8; i++) o0[i] = f2bf(tile[cg*16+i][jr]);
    for (int i = 0; i < 8; i++) o1[i] = f2bf(tile[cg*16+8+i][jr]);
    short* dst = Wt + (size_t)(j0 + jr) * DIM + c0 + cg * 16;
    *(short8*)dst = o0;
    *(short8*)(dst + 8) = o1;
}

// -------- GEMM: 128x128 tile, double-buffered DMA staging (1 barrier/kk), swapped-operand epilogue --------
__global__ void __launch_bounds__(256)
k_gemm(const short* __restrict__ T, const short* __restrict__ Wt,
       const float* __restrict__ bias, short* __restrict__ QVK,
       short* __restrict__ VT) {
    __shared__ __align__(16) short Abuf[2][128 * 64];
    __shared__ __align__(16) short Bbuf[2][128 * 64];
    int n0 = blockIdx.x * 128, j0 = blockIdx.y * 128, sb = blockIdx.z;
    int tid = threadIdx.x;
    int w = tid >> 6, l = tid & 63;
    int wr = w >> 1, wc = w & 1;
    int lrow = l & 15, quad = l >> 4;
    int r_in = (l >> 3) & 7, cc = l & 7;
    int ch = cc ^ r_in;                       // swizzled source chunk
    int sw0 = (quad ^ (lrow & 7)) * 8;        // frag-read chunk offset (shorts)
    const short* Ab = T + (size_t)sb * NTOK * DIM;
    f32x4 acc[4][4] = {};

    #pragma unroll
    for (int inst = 0; inst < 4; inst++) {
        int R = w * 32 + inst * 8 + r_in;
        gl2lds(Ab + (size_t)(n0 + R) * 512 + 0 * 64 + ch * 8, &Abuf[0][(w * 32 + inst * 8) * 64]);
        gl2lds(Wt + (size_t)(j0 + R) * 512 + 0 * 64 + ch * 8, &Bbuf[0][(w * 32 + inst * 8) * 64]);
    }
    int cur = 0;
    for (int kk = 0; kk < 8; kk++) {
        __syncthreads();                      // buf[cur] DMA drained; buf[cur^1] readers done
        if (kk + 1 < 8) {
            #pragma unroll
            for (int inst = 0; inst < 4; inst++) {
                int R = w * 32 + inst * 8 + r_in;
                gl2lds(Ab + (size_t)(n0 + R) * 512 + (kk + 1) * 64 + ch * 8,
                       &Abuf[cur ^ 1][(w * 32 + inst * 8) * 64]);
                gl2lds(Wt + (size_t)(j0 + R) * 512 + (kk + 1) * 64 + ch * 8,
                       &Bbuf[cur ^ 1][(w * 32 + inst * 8) * 64]);
            }
        }
        #pragma unroll
        for (int c2 = 0; c2 < 2; c2++) {
            int off = c2 ? (sw0 ^ 32) : sw0;
            short8 af[4], bf[4];
            #pragma unroll
            for (int i = 0; i < 4; i++)
                af[i] = *(const short8*)&Abuf[cur][(wr*64 + i*16 + lrow) * 64 + off];
            #pragma unroll
            for (int j = 0; j < 4; j++)
                bf[j] = *(const short8*)&Bbuf[cur][(wc*64 + j*16 + lrow) * 64 + off];
            #pragma unroll
            for (int i = 0; i < 4; i++)
                #pragma unroll
                for (int j = 0; j < 4; j++)   // SWAPPED: C rows = jj (bf), cols = n (af)
                    acc[i][j] = __builtin_amdgcn_mfma_f32_16x16x32_bf16(bf[j], af[i], acc[i][j], 0, 0, 0);
        }
        cur ^= 1;
    }
    // swapped C layout: element(i,j,reg): n = n0+wr*64+i*16+lrow, jj = j0+wc*64+j*16+quad*4+reg
    if (j0 >= 512 && j0 < 1024) {
        __syncthreads();               // main-loop LDS readers done
        short* sm = &Abuf[0][0];
        #pragma unroll
        for (int i = 0; i < 4; i++)
            #pragma unroll
            for (int j = 0; j < 4; j++) {
                int jb = wc * 64 + j * 16 + quad * 4;       // local jj base (mult of 4)
                int nloc = wr * 64 + i * 16 + lrow;
                float4 bv4 = *(const float4*)&bias[j0 + jb];
                float bvs[4] = {bv4.x, bv4.y, bv4.z, bv4.w};
                #pragma unroll
                for (int reg = 0; reg < 4; reg++) {
                    int jloc = jb + reg;
                    sm[jloc * 128 + (((nloc >> 3) ^ (jloc & 15)) * 8) + (nloc & 7)]
                        = f2bf(acc[i][j][reg] + bvs[reg]);
                }
            }
        __syncthreads();
        for (int slot = tid; slot < 2048; slot += 256) {
            int row = slot >> 4, seg = slot & 15;
            short8 v = *(const short8*)&sm[row * 128 + ((seg ^ (row & 15)) * 8)];
            *(short8*)(VT + ((size_t)sb * 512 + (j0 - 512) + row) * NTOK + n0 + seg * 8) = v;
        }
    } else {
        #pragma unroll
        for (int i = 0; i < 4; i++) {
            int n = n0 + wr * 64 + i * 16 + lrow;
            #pragma unroll
            for (int j = 0; j < 4; j++) {
                int jjb = j0 + wc * 64 + j * 16 + quad * 4;
                float4 bv4 = *(const float4*)&bias[jjb];
                float bvs[4] = {bv4.x, bv4.y, bv4.z, bv4.w};
                float sc = (jjb < 512) ? QSC : 1.0f;   // Q pre-scaled into exp2 domain
                sh4 pk;
                #pragma unroll
                for (int reg = 0; reg < 4; reg++)
                    pk[reg] = f2bf((acc[i][j][reg] + bvs[reg]) * sc);
                *(sh4*)&QVK[((size_t)sb * NTOK + n) * 1536 + jjb] = pk;   // 8B store
            }
        }
    }
}

// ---------------- flash attention: 128-row Q blocks, 4 waves x 32 Q-rows (R10 verified, 67.4us) ----------------
// R26: R13's direct-from-L2 fragment read was a 2.5x regression (67->166us,
// MfmaUtil 11.7): per-lane 3072B-stride loads put ~200-500cy L2 latency on the
// MFMA dependent path with no DMA running ahead. gl2lds staging + LDS dbuf IS
// the latency-hiding machinery (DMA queue a full tile ahead, decoupled from
// the wave). Reverted to the R10 structure verbatim.
__global__ void __launch_bounds__(256)
k_attn(const short* __restrict__ QVK, const short* __restrict__ VT,
       float* __restrict__ out, float* __restrict__ Opart,
       float* __restrict__ lbuf, int ntiles) {
    __shared__ __align__(16) short Kbuf[2][64 * 64];
    __shared__ __align__(16) short Vbuf[2][64 * 64];
    __shared__ __align__(16) short Qs[128 * 64];  // Q staging (128 rows); re-used as P (wave-private 32 rows)
    int id = blockIdx.x;
    int half = id / 576;              // KV slice index (0..ns-1)
    int rid = id % 576;
    int xcd = rid & 7, rem = rid >> 3;   // rem 0..71
    int qt = rem % 18, yhi = rem / 18;   // 18 q-tiles of 128 rows; yhi 0..3
    int yb = yhi * 8 + xcd;           // 0..31
    int br = yb >> 4;
    int b  = (yb >> 3) & 1;
    int h  = yb & 7;
    int tid = threadIdx.x;
    int w = tid >> 6, l = tid & 63;
    int lrow = l & 15, quad = l >> 4;
    int r_in = (l >> 3) & 7, cc = l & 7;
    int ch = cc ^ r_in;
    int sw0 = (quad ^ (lrow & 7)) * 8;
    int n0 = qt * 128;
    int m_base = half * ntiles * 64;
    const short* Qg = QVK + ((size_t)(br * 2 + b) * NTOK) * 1536 + h * 64;           // exp2-scaled Q
    const short* Kg = QVK + ((size_t)((1 - br) * 2 + b) * NTOK) * 1536 + 1024 + h * 64;
    const short* Vg = VT + ((size_t)(br * 2 + b) * 512 + h * 64) * NTOK;

    // stage Q (wave w: rows w*32..w*32+31 of the 128-row block)
    #pragma unroll
    for (int j = 0; j < 4; j++) {
        int R = w * 32 + j * 8 + r_in;
        gl2lds(Qg + (size_t)(n0 + R) * 1536 + ch * 8, &Qs[(w * 32 + j * 8) * 64]);
    }

    const short* KnA = Kg + (size_t)(m_base + w * 16 + r_in) * 1536 + ch * 8;
    const short* KnB = Kg + (size_t)(m_base + w * 16 + 8 + r_in) * 1536 + ch * 8;
    const short* VnA = Vg + (size_t)(w * 16 + r_in) * NTOK + m_base + ch * 8;
    const short* VnB = Vg + (size_t)(w * 16 + 8 + r_in) * NTOK + m_base + ch * 8;
    int lds_off = l * 8;              // lane slot (8-row linear groups)

    short8 ka = *(const short8*)(KnA);
    short8 kb = *(const short8*)(KnB);
    short8 va = *(const short8*)(VnA);
    short8 vb = *(const short8*)(VnB);
    KnA += (size_t)64 * 1536; KnB += (size_t)64 * 1536;
    VnA += 64; VnB += 64;

    __syncthreads();                  // Q staged (drains gl2lds + tile0 loads)
    short8 bq[2][2];
    #pragma unroll
    for (int qb = 0; qb < 2; qb++) {
        bq[qb][0] = *(const short8*)&Qs[(w * 32 + qb * 16 + lrow) * 64 + sw0];
        bq[qb][1] = *(const short8*)&Qs[(w * 32 + qb * 16 + lrow) * 64 + (sw0 ^ 32)];
    }
    short* Pw = &Qs[(w * 32) * 64];   // wave-private P region (32 rows)

    *(short8*)&Kbuf[0][(w * 16)     * 64 + lds_off] = ka;
    *(short8*)&Kbuf[0][(w * 16 + 8) * 64 + lds_off] = kb;
    *(short8*)&Vbuf[0][(w * 16)     * 64 + lds_off] = va;
    *(short8*)&Vbuf[0][(w * 16 + 8) * 64 + lds_off] = vb;
    ka = *(const short8*)(KnA);
    kb = *(const short8*)(KnB);
    va = *(const short8*)(VnA);
    vb = *(const short8*)(VnB);
    KnA += (size_t)64 * 1536; KnB += (size_t)64 * 1536;
    VnA += 64; VnB += 64;

    short8 ones;
    #pragma unroll
    for (int i = 0; i < 8; i++) ones[i] = (short)0x3F80;   // bf16 1.0

    f32x4 Oacc[2][4] = {};
    f32x4 lacc[2] = {};
    int cur = 0;

    for (int mt = 0; mt < ntiles; mt++) {
        __syncthreads();              // buf[cur]=tile mt visible; readers of buf[cur^1] done
        const short* Ks = Kbuf[cur];
        const short* Vs = Vbuf[cur];

        #pragma unroll
        for (int sub = 0; sub < 4; sub++) {
            short8 ak0 = *(const short8*)&Ks[(sub * 16 + lrow) * 64 + sw0];
            short8 ak1 = *(const short8*)&Ks[(sub * 16 + lrow) * 64 + (sw0 ^ 32)];
            #pragma unroll
            for (int qb = 0; qb < 2; qb++) {
                f32x4 a = {};
                a = __builtin_amdgcn_mfma_f32_16x16x32_bf16(ak0, bq[qb][0], a, 0, 0, 0);
                a = __builtin_amdgcn_mfma_f32_16x16x32_bf16(ak1, bq[qb][1], a, 0, 0, 0);
                float p0 = __builtin_amdgcn_exp2f(a[0]), p1 = __builtin_amdgcn_exp2f(a[1]);
                float p2 = __builtin_amdgcn_exp2f(a[2]), p3 = __builtin_amdgcn_exp2f(a[3]);
                uint2 pk;
                pk.x = __builtin_amdgcn_perm(fbits(p1), fbits(p0), 0x07060302u);
                pk.y = __builtin_amdgcn_perm(fbits(p3), fbits(p2), 0x07060302u);
                *(uint2*)&Pw[(qb * 16 + lrow) * 64 +
                             (((2 * sub + (quad >> 1)) ^ (lrow & 7)) * 8) + (quad & 1) * 4] = pk;
            }
        }

        short8 ap[2][2];
        #pragma unroll
        for (int qb = 0; qb < 2; qb++) {
            ap[qb][0] = *(const short8*)&Pw[(qb * 16 + lrow) * 64 + sw0];
            ap[qb][1] = *(const short8*)&Pw[(qb * 16 + lrow) * 64 + (sw0 ^ 32)];
            lacc[qb] = __builtin_amdgcn_mfma_f32_16x16x32_bf16(ones, ap[qb][0], lacc[qb], 0, 0, 0);
            lacc[qb] = __builtin_amdgcn_mfma_f32_16x16x32_bf16(ones, ap[qb][1], lacc[qb], 0, 0, 0);
        }
        #pragma unroll
        for (int ddt = 0; ddt < 4; ddt++) {
            short8 av0 = *(const short8*)&Vs[(ddt * 16 + lrow) * 64 + sw0];
            short8 av1 = *(const short8*)&Vs[(ddt * 16 + lrow) * 64 + (sw0 ^ 32)];
            #pragma unroll
            for (int qb = 0; qb < 2; qb++) {
                Oacc[qb][ddt] = __builtin_amdgcn_mfma_f32_16x16x32_bf16(av0, ap[qb][0], Oacc[qb][ddt], 0, 0, 0);
                Oacc[qb][ddt] = __builtin_amdgcn_mfma_f32_16x16x32_bf16(av1, ap[qb][1], Oacc[qb][ddt], 0, 0, 0);
            }
        }

        if (mt + 1 < ntiles) {
            *(short8*)&Kbuf[cur ^ 1][(w * 16)     * 64 + lds_off] = ka;
            *(short8*)&Kbuf[cur ^ 1][(w * 16 + 8) * 64 + lds_off] = kb;
            *(short8*)&Vbuf[cur ^ 1][(w * 16)     * 64 + lds_off] = va;
            *(short8*)&Vbuf[cur ^ 1][(w * 16 + 8) * 64 + lds_off] = vb;
        }
        if (mt + 2 < ntiles) {
            ka = *(const short8*)(KnA);
            kb = *(const short8*)(KnB);
            va = *(const short8*)(VnA);
            vb = *(const short8*)(VnB);
        }
        KnA += (size_t)64 * 1536; KnB += (size_t)64 * 1536;
        VnA += 64; VnB += 64;
        cur ^= 1;
    }

    // epilogue: unnormalized partial O + partial l (combined by k_norm)
    #pragma unroll
    for (int qb = 0; qb < 2; qb++) {
        int n = n0 + w * 32 + qb * 16 + lrow;
        if (quad == 0) lbuf[half * (32 * NTOK) + yb * NTOK + n] = lacc[qb][0];
        #pragma unroll
        for (int ddt = 0; ddt < 4; ddt++) {
            float4 o;
            o.x = Oacc[qb][ddt][0];
            o.y = Oacc[qb][ddt][1];
            o.z = Oacc[qb][ddt][2];
            o.w = Oacc[qb][ddt][3];
            if (half == 0) {
                if (br == 0)
                    *(float4*)&out[((size_t)b * NTOK + n) * 512 + h * 64 + ddt * 16 + quad * 4] = o;
                else
                    *(float4*)&out[(size_t)BNC + ((size_t)(h * 2 + b) * NTOK + n) * 64 + ddt * 16 + quad * 4] = o;
            } else {
                *(float4*)&Opart[(size_t)(half - 1) * 4718592 +
                                 ((size_t)yb * NTOK + n) * 64 + ddt * 16 + quad * 4] = o;
            }
        }
    }
}

// ---------------- combine + normalize: out = (out + sum Opart) / (sum l) ----------------
__global__ void __launch_bounds__(256)
k_norm(float* __restrict__ out, const float* __restrict__ Opart,
       const float* __restrict__ lbuf, int ns) {
    int i = blockIdx.x * 256 + threadIdx.x;   // float4 index, 1,179,648 total
    int o = i * 4;
    int yb, n, d;
    if (o < BNC) {
        int b = o / (NTOK * 512);
        int r = o % (NTOK * 512);
        n = r >> 9;
        int c = r & 511;
        d = c & 63;
        yb = b * 8 + (c >> 6);
    } else {
        int o2 = o - BNC;
        int hb = o2 / (NTOK * 64);
        n = (o2 >> 6) % NTOK;
        d = o2 & 63;
        yb = 16 + (hb & 1) * 8 + (hb >> 1);
    }
    int li = yb * NTOK + n;
    float lsum = 0.f;
    for (int k = 0; k < ns; k++) lsum += lbuf[k * (32 * NTOK) + li];
    float linv = 1.f / lsum;
    float4 a = *(const float4*)&out[o];
    for (int k = 1; k < ns; k++) {
        float4 q = *(const float4*)&Opart[(size_t)(k - 1) * 4718592 + (size_t)li * 64 + d];
        a.x += q.x; a.y += q.y; a.z += q.z; a.w += q.w;
    }
    a.x *= linv; a.y *= linv; a.z *= linv; a.w *= linv;
    *(float4*)&out[o] = a;
}

extern "C" void kernel_launch(void* const* d_in, const int* in_sizes, int n_in,
                              void* d_out, int out_size, void* d_ws, size_t ws_size,
                              hipStream_t stream) {
    const float* x     = (const float*)d_in[0];
    const float* y     = (const float*)d_in[1];
    const float* k_w   = (const float*)d_in[2];
    const float* k_b   = (const float*)d_in[3];
    const float* qv_w  = (const float*)d_in[4];
    const float* qv_b  = (const float*)d_in[5];
    const float* lnx_g = (const float*)d_in[6];
    const float* lnx_b = (const float*)d_in[7];
    const float* lny_g = (const float*)d_in[8];
    const float* lny_b = (const float*)d_in[9];
    float* out = (float*)d_out;

    char* ws = (char*)d_ws;
    float* bias = (float*)ws;                 // 6,144 B @ 0
    float* mu   = (float*)(ws + 6144);        // 36,864 B
    float* rs   = (float*)(ws + 43008);       // 36,864 B -> ends 79,872
    short* T    = (short*)(ws + 79872);       // 9,437,184 B -> ends 9,517,056
    short* Wt   = (short*)(ws + 9517056);     // 1,572,864 B -> ends 11,089,920
    short* QVK  = (short*)(ws + 11089920);    // 28,311,552 B -> ends 39,401,472
    short* VT   = (short*)(ws + 39401472);    // 9,437,184 B -> ends 48,838,656
    float* lbuf = (float*)(ws + 48838656);    // 1,179,648 B -> ends 50,018,304
    float* Opart= (float*)(ws + 50018304);    // up to 3 x 18,874,368 B -> ends 106,641,408

    // KV-split degree: 4 if the partial-O slabs fit in ws (R9/R10 proved they do), else 2.
    int ns = (ws_size >= 50018304ull + 3ull * 18874368ull) ? 4 : 2;
    int ntiles = 36 / ns;

    k_stats<<<144, 256, 0, stream>>>(x, y, mu, rs);
    k_pre  <<<1344, 256, 0, stream>>>(x, y, qv_w, k_w, qv_b, k_b,
                                      lnx_g, lnx_b, lny_g, lny_b, mu, rs, T, Wt, bias);
    k_gemm <<<dim3(18, 12, 4), 256, 0, stream>>>(T, Wt, bias, QVK, VT);
    k_attn <<<576 * ns, 256, 0, stream>>>(QVK, VT, out, Opart, lbuf, ntiles);
    k_norm <<<4608, 256, 0, stream>>>(out, Opart, lbuf, ns);
}

// Round 15
// 195.857 us; speedup vs baseline: 1.5434x; 1.0505x over previous
//
#include <hip/hip_runtime.h>

#define DIM 512
#define NTOK 2304
#define HEADS 8
#define HD 64
#define LN_EPS 1e-5f
#define BNC 2359296   // B*N*C = 2*2304*512
#define QSC 0.18033688011112042f   // 0.125 * log2(e): softmax in exp2 domain

typedef __attribute__((ext_vector_type(8))) short short8;
typedef __attribute__((ext_vector_type(4))) short sh4;
typedef __attribute__((ext_vector_type(4))) float f32x4;

__device__ __forceinline__ short f2bf(float f) {
    union { float f; unsigned u; } x; x.f = f;
    unsigned r = (x.u + 0x7fffu + ((x.u >> 16) & 1u)) >> 16;
    return (short)(r & 0xffffu);
}
__device__ __forceinline__ unsigned fbits(float f) {
    union { float f; unsigned u; } x; x.f = f; return x.u;
}
// async global->LDS DMA, 16B/lane; lds dest = wave-uniform base + lane*16
__device__ __forceinline__ void gl2lds(const short* g, short* l) {
    __builtin_amdgcn_global_load_lds(
        (const __attribute__((address_space(1))) unsigned int*)g,
        (__attribute__((address_space(3))) unsigned int*)l, 16, 0, 0);
}

// -------- fused pre: stats+normalize+transpose (blocks 0..1151) + weight transpose (1152..1343) --------
// R27: stats-split (R11) reverted -- it cost ~4us (extra launch + mu/rs
// round-trip) and its read-dedup saved nothing (redundant reads L2-absorbed).
__global__ void k_pre(const float* __restrict__ x, const float* __restrict__ y,
                      const float* __restrict__ qv_w, const float* __restrict__ k_w,
                      const float* __restrict__ qv_b, const float* __restrict__ k_b,
                      const float* __restrict__ gx, const float* __restrict__ bx,
                      const float* __restrict__ gy, const float* __restrict__ by,
                      short* __restrict__ T, short* __restrict__ Wt,
                      float* __restrict__ bias) {
    __shared__ __align__(16) float tile[64][65];
    __shared__ float pS[4][64], pQ[4][64];
    __shared__ float muL[64], rsL[64];
    int bkid = blockIdx.x, tid = threadIdx.x;
    if (bkid < 1152) {
        int nt = bkid % 36, ct = (bkid / 36) % 8, sb = bkid / 288;
        int s = sb >> 1, b = sb & 1;
        int n0 = nt * 64, c0 = ct * 64;
        const float* src = (s ? y : x) + (size_t)b * DIM * NTOK;
        // phase 1: LN stats for tokens n0..n0+63 (full 512-c read, 4-way split)
        int nl = tid & 63, part = tid >> 6;
        {
            const float* p = src + n0 + nl;
            float sum = 0.f, sq = 0.f;
            for (int c = part * 128; c < part * 128 + 128; c++) {
                float v = p[(size_t)c * NTOK];
                sum += v; sq += v * v;
            }
            pS[part][nl] = sum; pQ[part][nl] = sq;
        }
        __syncthreads();
        if (tid < 64) {
            float ts = pS[0][tid] + pS[1][tid] + pS[2][tid] + pS[3][tid];
            float tq = pQ[0][tid] + pQ[1][tid] + pQ[2][tid] + pQ[3][tid];
            float m = ts * (1.0f / DIM);
            float var = tq * (1.0f / DIM) - m * m;
            muL[tid] = m;
            rsL[tid] = rsqrtf(var + LN_EPS);
        }
        // phase 2: load c-tile, normalize, transpose-store
        for (int slot = tid; slot < 1024; slot += 256) {
            int r = slot >> 4, q = slot & 15;
            const float* p = src + (size_t)(c0 + r) * NTOK + n0 + q * 4;
            float4 v = *(const float4*)p;
            tile[r][q*4+0] = v.x; tile[r][q*4+1] = v.y;
            tile[r][q*4+2] = v.z; tile[r][q*4+3] = v.w;
        }
        __syncthreads();   // covers muL/rsL and tile
        const float* g  = s ? gy : gx;
        const float* be = s ? by : bx;
        int nr = tid >> 2, cg = tid & 3;
        float m = muL[nr], r_ = rsL[nr];
        short8 o0, o1;
        for (int i = 0; i < 8; i++) {
            int c = c0 + cg * 16 + i;
            o0[i] = f2bf((tile[cg*16+i][nr] - m) * r_ * g[c] + be[c]);
        }
        for (int i = 0; i < 8; i++) {
            int c = c0 + cg * 16 + 8 + i;
            o1[i] = f2bf((tile[cg*16+8+i][nr] - m) * r_ * g[c] + be[c]);
        }
        short* dst = T + ((size_t)sb * NTOK + n0 + nr) * DIM + c0 + cg * 16;
        *(short8*)dst = o0;
        *(short8*)(dst + 8) = o1;
        return;
    }
    // ---- weight transpose blocks ----
    int idx = bkid - 1152;
    int jt = idx % 24, ct = idx / 24;
    int j0 = jt * 64, c0 = ct * 64;
    if (ct == 0 && tid < 64) {
        int j = j0 + tid;
        bias[j] = (j < 1024) ? qv_b[j] : k_b[j - 1024];
    }
    for (int slot = tid; slot < 1024; slot += 256) {
        int r = slot >> 4, q = slot & 15;
        int c = c0 + r;
        float4 v;
        if (j0 < 1024) v = *(const float4*)(qv_w + (size_t)c * 1024 + j0 + q * 4);
        else           v = *(const float4*)(k_w  + (size_t)c * 512  + (j0 - 1024) + q * 4);
        tile[r][q*4+0] = v.x; tile[r][q*4+1] = v.y;
        tile[r][q*4+2] = v.z; tile[r][q*4+3] = v.w;
    }
    __syncthreads();
    int jr = tid >> 2, cg = tid & 3;
    short8 o0, o1;
    for (int i = 0; i < 8; i++) o0[i] = f2bf(tile[cg*16+i][jr]);
    for (int i = 0; i < 8; i++) o1[i] = f2bf(tile[cg*16+8+i][jr]);
    short* dst = Wt + (size_t)(j0 + jr) * DIM + c0 + cg * 16;
    *(short8*)dst = o0;
    *(short8*)(dst + 8) = o1;
}

// -------- GEMM: 128x128 tile, double-buffered DMA staging (1 barrier/kk), swapped-operand epilogue --------
__global__ void __launch_bounds__(256)
k_gemm(const short* __restrict__ T, const short* __restrict__ Wt,
       const float* __restrict__ bias, short* __restrict__ QVK,
       short* __restrict__ VT) {
    __shared__ __align__(16) short Abuf[2][128 * 64];
    __shared__ __align__(16) short Bbuf[2][128 * 64];
    int n0 = blockIdx.x * 128, j0 = blockIdx.y * 128, sb = blockIdx.z;
    int tid = threadIdx.x;
    int w = tid >> 6, l = tid & 63;
    int wr = w >> 1, wc = w & 1;
    int lrow = l & 15, quad = l >> 4;
    int r_in = (l >> 3) & 7, cc = l & 7;
    int ch = cc ^ r_in;                       // swizzled source chunk
    int sw0 = (quad ^ (lrow & 7)) * 8;        // frag-read chunk offset (shorts)
    const short* Ab = T + (size_t)sb * NTOK * DIM;
    f32x4 acc[4][4] = {};

    #pragma unroll
    for (int inst = 0; inst < 4; inst++) {
        int R = w * 32 + inst * 8 + r_in;
        gl2lds(Ab + (size_t)(n0 + R) * 512 + 0 * 64 + ch * 8, &Abuf[0][(w * 32 + inst * 8) * 64]);
        gl2lds(Wt + (size_t)(j0 + R) * 512 + 0 * 64 + ch * 8, &Bbuf[0][(w * 32 + inst * 8) * 64]);
    }
    int cur = 0;
    for (int kk = 0; kk < 8; kk++) {
        __syncthreads();                      // buf[cur] DMA drained; buf[cur^1] readers done
        if (kk + 1 < 8) {
            #pragma unroll
            for (int inst = 0; inst < 4; inst++) {
                int R = w * 32 + inst * 8 + r_in;
                gl2lds(Ab + (size_t)(n0 + R) * 512 + (kk + 1) * 64 + ch * 8,
                       &Abuf[cur ^ 1][(w * 32 + inst * 8) * 64]);
                gl2lds(Wt + (size_t)(j0 + R) * 512 + (kk + 1) * 64 + ch * 8,
                       &Bbuf[cur ^ 1][(w * 32 + inst * 8) * 64]);
            }
        }
        #pragma unroll
        for (int c2 = 0; c2 < 2; c2++) {
            int off = c2 ? (sw0 ^ 32) : sw0;
            short8 af[4], bf[4];
            #pragma unroll
            for (int i = 0; i < 4; i++)
                af[i] = *(const short8*)&Abuf[cur][(wr*64 + i*16 + lrow) * 64 + off];
            #pragma unroll
            for (int j = 0; j < 4; j++)
                bf[j] = *(const short8*)&Bbuf[cur][(wc*64 + j*16 + lrow) * 64 + off];
            #pragma unroll
            for (int i = 0; i < 4; i++)
                #pragma unroll
                for (int j = 0; j < 4; j++)   // SWAPPED: C rows = jj (bf), cols = n (af)
                    acc[i][j] = __builtin_amdgcn_mfma_f32_16x16x32_bf16(bf[j], af[i], acc[i][j], 0, 0, 0);
        }
        cur ^= 1;
    }
    // swapped C layout: element(i,j,reg): n = n0+wr*64+i*16+lrow, jj = j0+wc*64+j*16+quad*4+reg
    if (j0 >= 512 && j0 < 1024) {
        __syncthreads();               // main-loop LDS readers done
        short* sm = &Abuf[0][0];
        #pragma unroll
        for (int i = 0; i < 4; i++)
            #pragma unroll
            for (int j = 0; j < 4; j++) {
                int jb = wc * 64 + j * 16 + quad * 4;       // local jj base (mult of 4)
                int nloc = wr * 64 + i * 16 + lrow;
                float4 bv4 = *(const float4*)&bias[j0 + jb];
                float bvs[4] = {bv4.x, bv4.y, bv4.z, bv4.w};
                #pragma unroll
                for (int reg = 0; reg < 4; reg++) {
                    int jloc = jb + reg;
                    sm[jloc * 128 + (((nloc >> 3) ^ (jloc & 15)) * 8) + (nloc & 7)]
                        = f2bf(acc[i][j][reg] + bvs[reg]);
                }
            }
        __syncthreads();
        for (int slot = tid; slot < 2048; slot += 256) {
            int row = slot >> 4, seg = slot & 15;
            short8 v = *(const short8*)&sm[row * 128 + ((seg ^ (row & 15)) * 8)];
            *(short8*)(VT + ((size_t)sb * 512 + (j0 - 512) + row) * NTOK + n0 + seg * 8) = v;
        }
    } else {
        #pragma unroll
        for (int i = 0; i < 4; i++) {
            int n = n0 + wr * 64 + i * 16 + lrow;
            #pragma unroll
            for (int j = 0; j < 4; j++) {
                int jjb = j0 + wc * 64 + j * 16 + quad * 4;
                float4 bv4 = *(const float4*)&bias[jjb];
                float bvs[4] = {bv4.x, bv4.y, bv4.z, bv4.w};
                float sc = (jjb < 512) ? QSC : 1.0f;   // Q pre-scaled into exp2 domain
                sh4 pk;
                #pragma unroll
                for (int reg = 0; reg < 4; reg++)
                    pk[reg] = f2bf((acc[i][j][reg] + bvs[reg]) * sc);
                *(sh4*)&QVK[((size_t)sb * NTOK + n) * 1536 + jjb] = pk;   // 8B store
            }
        }
    }
}

// ---------------- flash attention: 128-row Q blocks, 4 waves x 32 Q-rows (R10 core, verified 67us) ----------------
// R27: ns=2 (grid 1152, 18 tiles/block). Ledger: ns is duration-neutral for
// attn (R6 ns=2 1-qb 76us ~= R9 ns=4 1-qb 78us; R10's gain was the 2-qb
// amortization) but ns=4 costs ~6-8us in k_norm traffic + Opart write drain.
__global__ void __launch_bounds__(256)
k_attn(const short* __restrict__ QVK, const short* __restrict__ VT,
       float* __restrict__ out, float* __restrict__ Opart,
       float* __restrict__ lbuf, int ntiles) {
    __shared__ __align__(16) short Kbuf[2][64 * 64];
    __shared__ __align__(16) short Vbuf[2][64 * 64];
    __shared__ __align__(16) short Qs[128 * 64];  // Q staging (128 rows); re-used as P (wave-private 32 rows)
    int id = blockIdx.x;
    int half = id / 576;              // KV slice index (0..ns-1)
    int rid = id % 576;
    int xcd = rid & 7, rem = rid >> 3;   // rem 0..71
    int qt = rem % 18, yhi = rem / 18;   // 18 q-tiles of 128 rows; yhi 0..3
    int yb = yhi * 8 + xcd;           // 0..31
    int br = yb >> 4;
    int b  = (yb >> 3) & 1;
    int h  = yb & 7;
    int tid = threadIdx.x;
    int w = tid >> 6, l = tid & 63;
    int lrow = l & 15, quad = l >> 4;
    int r_in = (l >> 3) & 7, cc = l & 7;
    int ch = cc ^ r_in;
    int sw0 = (quad ^ (lrow & 7)) * 8;
    int n0 = qt * 128;
    int m_base = half * ntiles * 64;
    const short* Qg = QVK + ((size_t)(br * 2 + b) * NTOK) * 1536 + h * 64;           // exp2-scaled Q
    const short* Kg = QVK + ((size_t)((1 - br) * 2 + b) * NTOK) * 1536 + 1024 + h * 64;
    const short* Vg = VT + ((size_t)(br * 2 + b) * 512 + h * 64) * NTOK;

    // stage Q (wave w: rows w*32..w*32+31 of the 128-row block)
    #pragma unroll
    for (int j = 0; j < 4; j++) {
        int R = w * 32 + j * 8 + r_in;
        gl2lds(Qg + (size_t)(n0 + R) * 1536 + ch * 8, &Qs[(w * 32 + j * 8) * 64]);
    }

    const short* KnA = Kg + (size_t)(m_base + w * 16 + r_in) * 1536 + ch * 8;
    const short* KnB = Kg + (size_t)(m_base + w * 16 + 8 + r_in) * 1536 + ch * 8;
    const short* VnA = Vg + (size_t)(w * 16 + r_in) * NTOK + m_base + ch * 8;
    const short* VnB = Vg + (size_t)(w * 16 + 8 + r_in) * NTOK + m_base + ch * 8;
    int lds_off = l * 8;              // lane slot (8-row linear groups)

    short8 ka = *(const short8*)(KnA);
    short8 kb = *(const short8*)(KnB);
    short8 va = *(const short8*)(VnA);
    short8 vb = *(const short8*)(VnB);
    KnA += (size_t)64 * 1536; KnB += (size_t)64 * 1536;
    VnA += 64; VnB += 64;

    __syncthreads();                  // Q staged (drains gl2lds + tile0 loads)
    short8 bq[2][2];
    #pragma unroll
    for (int qb = 0; qb < 2; qb++) {
        bq[qb][0] = *(const short8*)&Qs[(w * 32 + qb * 16 + lrow) * 64 + sw0];
        bq[qb][1] = *(const short8*)&Qs[(w * 32 + qb * 16 + lrow) * 64 + (sw0 ^ 32)];
    }
    short* Pw = &Qs[(w * 32) * 64];   // wave-private P region (32 rows)

    *(short8*)&Kbuf[0][(w * 16)     * 64 + lds_off] = ka;
    *(short8*)&Kbuf[0][(w * 16 + 8) * 64 + lds_off] = kb;
    *(short8*)&Vbuf[0][(w * 16)     * 64 + lds_off] = va;
    *(short8*)&Vbuf[0][(w * 16 + 8) * 64 + lds_off] = vb;
    ka = *(const short8*)(KnA);
    kb = *(const short8*)(KnB);
    va = *(const short8*)(VnA);
    vb = *(const short8*)(VnB);
    KnA += (size_t)64 * 1536; KnB += (size_t)64 * 1536;
    VnA += 64; VnB += 64;

    short8 ones;
    #pragma unroll
    for (int i = 0; i < 8; i++) ones[i] = (short)0x3F80;   // bf16 1.0

    f32x4 Oacc[2][4] = {};
    f32x4 lacc[2] = {};
    int cur = 0;

    for (int mt = 0; mt < ntiles; mt++) {
        __syncthreads();              // buf[cur]=tile mt visible; readers of buf[cur^1] done
        const short* Ks = Kbuf[cur];
        const short* Vs = Vbuf[cur];

        #pragma unroll
        for (int sub = 0; sub < 4; sub++) {
            short8 ak0 = *(const short8*)&Ks[(sub * 16 + lrow) * 64 + sw0];
            short8 ak1 = *(const short8*)&Ks[(sub * 16 + lrow) * 64 + (sw0 ^ 32)];
            #pragma unroll
            for (int qb = 0; qb < 2; qb++) {
                f32x4 a = {};
                a = __builtin_amdgcn_mfma_f32_16x16x32_bf16(ak0, bq[qb][0], a, 0, 0, 0);
                a = __builtin_amdgcn_mfma_f32_16x16x32_bf16(ak1, bq[qb][1], a, 0, 0, 0);
                float p0 = __builtin_amdgcn_exp2f(a[0]), p1 = __builtin_amdgcn_exp2f(a[1]);
                float p2 = __builtin_amdgcn_exp2f(a[2]), p3 = __builtin_amdgcn_exp2f(a[3]);
                uint2 pk;
                pk.x = __builtin_amdgcn_perm(fbits(p1), fbits(p0), 0x07060302u);
                pk.y = __builtin_amdgcn_perm(fbits(p3), fbits(p2), 0x07060302u);
                *(uint2*)&Pw[(qb * 16 + lrow) * 64 +
                             (((2 * sub + (quad >> 1)) ^ (lrow & 7)) * 8) + (quad & 1) * 4] = pk;
            }
        }

        short8 ap[2][2];
        #pragma unroll
        for (int qb = 0; qb < 2; qb++) {
            ap[qb][0] = *(const short8*)&Pw[(qb * 16 + lrow) * 64 + sw0];
            ap[qb][1] = *(const short8*)&Pw[(qb * 16 + lrow) * 64 + (sw0 ^ 32)];
            lacc[qb] = __builtin_amdgcn_mfma_f32_16x16x32_bf16(ones, ap[qb][0], lacc[qb], 0, 0, 0);
            lacc[qb] = __builtin_amdgcn_mfma_f32_16x16x32_bf16(ones, ap[qb][1], lacc[qb], 0, 0, 0);
        }
        #pragma unroll
        for (int ddt = 0; ddt < 4; ddt++) {
            short8 av0 = *(const short8*)&Vs[(ddt * 16 + lrow) * 64 + sw0];
            short8 av1 = *(const short8*)&Vs[(ddt * 16 + lrow) * 64 + (sw0 ^ 32)];
            #pragma unroll
            for (int qb = 0; qb < 2; qb++) {
                Oacc[qb][ddt] = __builtin_amdgcn_mfma_f32_16x16x32_bf16(av0, ap[qb][0], Oacc[qb][ddt], 0, 0, 0);
                Oacc[qb][ddt] = __builtin_amdgcn_mfma_f32_16x16x32_bf16(av1, ap[qb][1], Oacc[qb][ddt], 0, 0, 0);
            }
        }

        if (mt + 1 < ntiles) {
            *(short8*)&Kbuf[cur ^ 1][(w * 16)     * 64 + lds_off] = ka;
            *(short8*)&Kbuf[cur ^ 1][(w * 16 + 8) * 64 + lds_off] = kb;
            *(short8*)&Vbuf[cur ^ 1][(w * 16)     * 64 + lds_off] = va;
            *(short8*)&Vbuf[cur ^ 1][(w * 16 + 8) * 64 + lds_off] = vb;
        }
        if (mt + 2 < ntiles) {
            ka = *(const short8*)(KnA);
            kb = *(const short8*)(KnB);
            va = *(const short8*)(VnA);
            vb = *(const short8*)(VnB);
        }
        KnA += (size_t)64 * 1536; KnB += (size_t)64 * 1536;
        VnA += 64; VnB += 64;
        cur ^= 1;
    }

    // epilogue: unnormalized partial O + partial l (combined by k_norm)
    #pragma unroll
    for (int qb = 0; qb < 2; qb++) {
        int n = n0 + w * 32 + qb * 16 + lrow;
        if (quad == 0) lbuf[half * (32 * NTOK) + yb * NTOK + n] = lacc[qb][0];
        #pragma unroll
        for (int ddt = 0; ddt < 4; ddt++) {
            float4 o;
            o.x = Oacc[qb][ddt][0];
            o.y = Oacc[qb][ddt][1];
            o.z = Oacc[qb][ddt][2];
            o.w = Oacc[qb][ddt][3];
            if (half == 0) {
                if (br == 0)
                    *(float4*)&out[((size_t)b * NTOK + n) * 512 + h * 64 + ddt * 16 + quad * 4] = o;
                else
                    *(float4*)&out[(size_t)BNC + ((size_t)(h * 2 + b) * NTOK + n) * 64 + ddt * 16 + quad * 4] = o;
            } else {
                *(float4*)&Opart[(size_t)(half - 1) * 4718592 +
                                 ((size_t)yb * NTOK + n) * 64 + ddt * 16 + quad * 4] = o;
            }
        }
    }
}

// ---------------- combine + normalize: out = (out + sum Opart) / (sum l) ----------------
__global__ void __launch_bounds__(256)
k_norm(float* __restrict__ out, const float* __restrict__ Opart,
       const float* __restrict__ lbuf, int ns) {
    int i = blockIdx.x * 256 + threadIdx.x;   // float4 index, 1,179,648 total
    int o = i * 4;
    int yb, n, d;
    if (o < BNC) {
        int b = o / (NTOK * 512);
        int r = o % (NTOK * 512);
        n = r >> 9;
        int c = r & 511;
        d = c & 63;
        yb = b * 8 + (c >> 6);
    } else {
        int o2 = o - BNC;
        int hb = o2 / (NTOK * 64);
        n = (o2 >> 6) % NTOK;
        d = o2 & 63;
        yb = 16 + (hb & 1) * 8 + (hb >> 1);
    }
    int li = yb * NTOK + n;
    float lsum = 0.f;
    for (int k = 0; k < ns; k++) lsum += lbuf[k * (32 * NTOK) + li];
    float linv = 1.f / lsum;
    float4 a = *(const float4*)&out[o];
    for (int k = 1; k < ns; k++) {
        float4 q = *(const float4*)&Opart[(size_t)(k - 1) * 4718592 + (size_t)li * 64 + d];
        a.x += q.x; a.y += q.y; a.z += q.z; a.w += q.w;
    }
    a.x *= linv; a.y *= linv; a.z *= linv; a.w *= linv;
    *(float4*)&out[o] = a;
}

extern "C" void kernel_launch(void* const* d_in, const int* in_sizes, int n_in,
                              void* d_out, int out_size, void* d_ws, size_t ws_size,
                              hipStream_t stream) {
    const float* x     = (const float*)d_in[0];
    const float* y     = (const float*)d_in[1];
    const float* k_w   = (const float*)d_in[2];
    const float* k_b   = (const float*)d_in[3];
    const float* qv_w  = (const float*)d_in[4];
    const float* qv_b  = (const float*)d_in[5];
    const float* lnx_g = (const float*)d_in[6];
    const float* lnx_b = (const float*)d_in[7];
    const float* lny_g = (const float*)d_in[8];
    const float* lny_b = (const float*)d_in[9];
    float* out = (float*)d_out;

    char* ws = (char*)d_ws;
    float* bias = (float*)ws;                 // 6,144 B @ 0
    short* T    = (short*)(ws + 6144);        // 9,437,184 B -> ends 9,443,328
    short* Wt   = (short*)(ws + 9443328);     // 1,572,864 B -> ends 11,016,192
    short* QVK  = (short*)(ws + 11016192);    // 28,311,552 B -> ends 39,327,744
    short* VT   = (short*)(ws + 39327744);    // 9,437,184 B -> ends 48,764,928
    float* lbuf = (float*)(ws + 48764928);    // 2 x 294,912 B -> ends 49,354,752
    float* Opart= (float*)(ws + 49354752);    // 1 x 18,874,368 B -> ends 68,229,120

    const int ns = 2;                 // R27: ns duration-neutral for attn; ns=2 halves norm/Opart traffic
    const int ntiles = 36 / ns;       // 18

    k_pre  <<<1344, 256, 0, stream>>>(x, y, qv_w, k_w, qv_b, k_b,
                                      lnx_g, lnx_b, lny_g, lny_b, T, Wt, bias);
    k_gemm <<<dim3(18, 12, 4), 256, 0, stream>>>(T, Wt, bias, QVK, VT);
    k_attn <<<576 * ns, 256, 0, stream>>>(QVK, VT, out, Opart, lbuf, ntiles);
    k_norm <<<4608, 256, 0, stream>>>(out, Opart, lbuf, ns);
}